// Round 3
// baseline (409.467 us; speedup 1.0000x reference)
//
#include <hip/hip_runtime.h>
#include <math.h>

// Problem constants (B=2, N=2048, C=1024, F=4096, H=16, D=64)
#define BN  4096
#define SEQ 2048
#define CH  1024
#define FF  4096
#define NH  16
#define HD  64

typedef short bf16x8 __attribute__((ext_vector_type(8)));
typedef float f32x4  __attribute__((ext_vector_type(4)));

#define MFMA16(a,b,c) __builtin_amdgcn_mfma_f32_16x16x32_bf16(a,b,c,0,0,0)

__device__ __forceinline__ unsigned short f2b(float f){
  unsigned u = __float_as_uint(f);
  u += 0x7fffu + ((u>>16)&1u);          // RNE to bf16
  return (unsigned short)(u>>16);
}

// pack two fp32 -> two bf16 (truncation) in ONE v_perm_b32
__device__ __forceinline__ unsigned pk2(float a, float b){
  return __builtin_amdgcn_perm(__float_as_uint(b), __float_as_uint(a), 0x07060302u);
}

#if __has_builtin(__builtin_amdgcn_exp2f)
__device__ __forceinline__ float fexp2(float x){ return __builtin_amdgcn_exp2f(x); }
#else
__device__ __forceinline__ float fexp2(float x){
  float r; asm("v_exp_f32 %0, %1" : "=v"(r) : "v"(x)); return r;
}
#endif

__device__ __forceinline__ void gl2lds16(const void* g, void* l){
  __builtin_amdgcn_global_load_lds(
      (__attribute__((address_space(1))) void*)g,
      (__attribute__((address_space(3))) void*)l, 16, 0, 0);
}

// bijective chunked XCD swizzle (T1): blocks with dispatch id d land on XCD
// d%8; remap so each XCD processes a CONTIGUOUS chunk of logical work ids.
// Requires nwg % 8 == 0 (all our grids satisfy this).
__device__ __forceinline__ unsigned xcd_chunk(unsigned id, unsigned nwg){
  const unsigned cpx = nwg >> 3;
  return (id & 7u)*cpx + (id >> 3);
}

// ---------------- transpose + fp32->bf16 convert (out[s][r] = in[r][s]*scale)
__global__ __launch_bounds__(256) void transpose_cvt(const float* __restrict__ in,
    unsigned short* __restrict__ out, int R, int S, float scale)
{
  __shared__ float tile[64][65];
  const int tid = threadIdx.x;
  const int tx = tid & 63, ty = tid >> 6;
  const int s0 = blockIdx.x * 64, r0 = blockIdx.y * 64;
  #pragma unroll
  for (int j = 0; j < 16; j++){
    int r = ty + j*4;
    tile[r][tx] = in[(size_t)(r0 + r)*S + s0 + tx];
  }
  __syncthreads();
  #pragma unroll
  for (int j = 0; j < 16; j++){
    int s = ty + j*4;
    out[(size_t)(s0 + s)*R + r0 + tx] = f2b(tile[tx][s] * scale);
  }
}

// ---------------- LayerNorm (fp32 in, bf16 out), one block per row of 1024
__global__ __launch_bounds__(256) void ln_kernel(const float* __restrict__ x,
    const float* __restrict__ gamma, const float* __restrict__ beta,
    unsigned short* __restrict__ out)
{
  const int row = blockIdx.x, tid = threadIdx.x;
  const float4 xv = ((const float4*)(x + (size_t)row*CH))[tid];
  float s  = xv.x + xv.y + xv.z + xv.w;
  float ss = xv.x*xv.x + xv.y*xv.y + xv.z*xv.z + xv.w*xv.w;
  #pragma unroll
  for (int off = 1; off < 64; off <<= 1){
    s  += __shfl_xor(s,  off, 64);
    ss += __shfl_xor(ss, off, 64);
  }
  __shared__ float red[8];
  const int w = tid >> 6;
  if ((tid & 63) == 0){ red[w] = s; red[4+w] = ss; }
  __syncthreads();
  s  = red[0]+red[1]+red[2]+red[3];
  ss = red[4]+red[5]+red[6]+red[7];
  const float mu   = s * (1.f/CH);
  const float rstd = rsqrtf(ss*(1.f/CH) - mu*mu + 1e-6f);
  const float4 g = ((const float4*)gamma)[tid];
  const float4 b = ((const float4*)beta )[tid];
  ushort4 o;
  o.x = f2b((xv.x-mu)*rstd*g.x + b.x);
  o.y = f2b((xv.y-mu)*rstd*g.y + b.y);
  o.z = f2b((xv.z-mu)*rstd*g.z + b.z);
  o.w = f2b((xv.w-mu)*rstd*g.w + b.w);
  ((ushort4*)(out + (size_t)row*CH))[tid] = o;
}

// ---------------- big-tile GEMM: C[M,Nn] = A[M,K](bf16) * Bt[Nn,K]^T(bf16)
// 256x256 tile, 8 waves (2M x 4N), per-wave 128x64 output (af[8] x bf[4]
// register blocking = 0.375 KB LDS read per MFMA), BK=64, double-buffered:
// per K-tile: stage next tile (other buffer) at top, two kc-phases split by
// sched_barrier(0), ONE __syncthreads at K-tile end. LDS 16B-chunk XOR
// swizzle (slot s of row r holds chunk s^(r&7)) - conflict-free ds_read_b128.
// setprio(1) around MFMA clusters (T5; phase-split structure).
// OMODE: 0 = fp32 out (+SPLITK atomic), 1 = bf16 out, 3 = fused QKV epilogue.
// OMODE 1/3: per-wave 16KB LDS scratch stage then 16B coalesced stores.
template<int BIAS,int GELU,int RES,int OMODE,int SPLITK>
__global__ __launch_bounds__(512,2) void gemm256(const unsigned short* __restrict__ A,
    const unsigned short* __restrict__ Bt, const float* __restrict__ bias,
    const float* __restrict__ resid, float* __restrict__ outF,
    unsigned short* __restrict__ outB, unsigned short* __restrict__ outK,
    unsigned short* __restrict__ outV, int M, int Nn, int K)
{
  __shared__ __align__(16) char lds[131072];   // A dbuf 64K | B dbuf 64K
  const int tid = threadIdx.x;
  const int w = tid >> 6, lane = tid & 63;
  const int quad = lane >> 4, l16 = lane & 15;
  const unsigned Wid = xcd_chunk(blockIdx.y*gridDim.x + blockIdx.x,
                                 gridDim.x*gridDim.y);
  const int bx = Wid % gridDim.x, by = Wid / gridDim.x;
  const int m0 = by*256, n0 = bx*256;
  const int wm = (w >> 2)*128, wn = (w & 3)*64;
  const int srow = lane >> 3, sslot = lane & 7;
  f32x4 acc[8][4] = {};
  const int kseg = SPLITK > 1 ? K / SPLITK : K;
  const int kBeg = SPLITK > 1 ? blockIdx.z * kseg : 0;
  const int nt = kseg >> 6;

  auto STAGE = [&](int buf, int k0){
    char* Ad = lds + buf*32768;
    char* Bd = lds + 65536 + buf*32768;
    #pragma unroll
    for (int i = 0; i < 4; i++){
      const int ci = w*4 + i;              // 1KB wave-chunk: rows [ci*8,ci*8+8)
      const int r = ci*8 + srow;
      const int c = sslot ^ srow;          // (r&7)==srow
      gl2lds16(A  + (size_t)(m0 + r)*K + k0 + c*8, Ad + ci*1024);
      gl2lds16(Bt + (size_t)(n0 + r)*K + k0 + c*8, Bd + ci*1024);
    }
  };

  STAGE(0, kBeg);
  __syncthreads();
  for (int kt = 0; kt < nt; kt++){
    const int cur = kt & 1;
    if (kt + 1 < nt) STAGE(cur ^ 1, kBeg + (kt+1)*64);
    const unsigned short* Ac = (const unsigned short*)(lds + cur*32768);
    const unsigned short* Bc = (const unsigned short*)(lds + 65536 + cur*32768);
    #pragma unroll
    for (int h = 0; h < 2; h++){
      bf16x8 af[8], bf[4];
      #pragma unroll
      for (int mf = 0; mf < 8; mf++){
        const int r = wm + mf*16 + l16;
        af[mf] = *(const bf16x8*)(Ac + r*64 + (((h*4 + quad) ^ (r & 7))*8));
      }
      #pragma unroll
      for (int nf = 0; nf < 4; nf++){
        const int r = wn + nf*16 + l16;
        bf[nf] = *(const bf16x8*)(Bc + r*64 + (((h*4 + quad) ^ (r & 7))*8));
      }
      __builtin_amdgcn_s_setprio(1);
      #pragma unroll
      for (int mf = 0; mf < 8; mf++)
        #pragma unroll
        for (int nf = 0; nf < 4; nf++)
          acc[mf][nf] = MFMA16(af[mf], bf[nf], acc[mf][nf]);
      __builtin_amdgcn_s_setprio(0);
      if (h == 0) __builtin_amdgcn_sched_barrier(0);
    }
    __syncthreads();    // vmcnt(0)+lgkmcnt(0)+barrier: K-tile boundary
  }

  // ---- epilogue.  C/D: col = l16 (within 16-frag), row = quad*4 + reg
  const int colb = n0 + wn;          // 64-aligned
  const int row0 = m0 + wm;          // 128-aligned
  if (OMODE == 1 || OMODE == 3){
    unsigned short* scr = (unsigned short*)lds + w*8192;   // 16KB per wave
    const int cg = (OMODE == 3) ? (colb >> 10) : 0;
    #pragma unroll
    for (int nf = 0; nf < 4; nf++){
      const int col = colb + nf*16 + l16;
      const float bv = BIAS ? bias[col] : 0.f;
      #pragma unroll
      for (int mf = 0; mf < 8; mf++){
        #pragma unroll
        for (int r = 0; r < 4; r++){
          const int rl = mf*16 + quad*4 + r;         // local row 0..127
          float v = acc[mf][nf][r] + bv;
          if (GELU) v = 0.5f*v*(1.f + erff(v*0.70710678118654752f));
          if (RES)  v += resid[(size_t)(row0 + rl)*Nn + col];
          const unsigned short b16 = f2b(v);
          if (OMODE == 3 && cg == 2){
            // V: scratch [64 d][128 tok], tokens pi-permuted within 64-blocks
            const int dl = nf*16 + l16;
            scr[dl*128 + (rl & ~63) + (((rl & 15) << 2) | ((rl >> 4) & 3))] = b16;
          } else {
            scr[rl*64 + nf*16 + l16] = b16;
          }
        }
      }
    }
    // coalesced readback: 16 x 16B stores per lane (same-wave data, no barrier)
    if (OMODE == 3 && cg == 2){
      const int bb = row0 >> 11;
      const int hh = (colb & (CH-1)) >> 6;
      #pragma unroll
      for (int j = 0; j < 16; j++){
        const int dl = j*4 + quad;
        const int t8 = l16*8;
        const bf16x8 vv = *(const bf16x8*)(scr + dl*128 + t8);
        *(bf16x8*)(outV + ((size_t)((bb*NH + hh)*HD) + dl)*SEQ
                        + (row0 & (SEQ-1)) + t8) = vv;
      }
    } else {
      const int sl = (lane & 7)*8;
      #pragma unroll
      for (int j = 0; j < 16; j++){
        const int rr = j*8 + (lane >> 3);
        const bf16x8 vv = *(const bf16x8*)(scr + rr*64 + sl);
        if (OMODE == 1)
          *(bf16x8*)(outB + (size_t)(row0 + rr)*Nn + colb + sl) = vv;
        else if (cg == 0)
          *(bf16x8*)(outB + (size_t)(row0 + rr)*CH + (colb & (CH-1)) + sl) = vv;
        else
          *(bf16x8*)(outK + (size_t)(row0 + rr)*CH + (colb & (CH-1)) + sl) = vv;
      }
    }
    return;
  }
  // OMODE 0: fp32 direct (optionally split-K atomic)
  #pragma unroll
  for (int nf = 0; nf < 4; nf++){
    const int col = colb + nf*16 + l16;
    const float bv = BIAS ? bias[col] : 0.f;
    #pragma unroll
    for (int mf = 0; mf < 8; mf++){
      #pragma unroll
      for (int r = 0; r < 4; r++){
        const int row = row0 + mf*16 + quad*4 + r;
        float v = acc[mf][nf][r];
        if (SPLITK > 1){
          if (blockIdx.z == 0){
            if (BIAS) v += bias[col];
            if (RES)  v += resid[(size_t)row*Nn + col];
          }
          atomicAdd(&outF[(size_t)row*Nn + col], v);
          continue;
        }
        v += bv;
        if (GELU) v = 0.5f*v*(1.f + erff(v*0.70710678118654752f));
        if (RES)  v += resid[(size_t)row*Nn + col];
        outF[(size_t)row*Nn + col] = v;
      }
    }
  }
}

// ---------------- 128-tile GEMM (kept for Wp: M=4096, N=1024, K=1024)
// 2-phase double-buffered, 4 waves; see round-1 notes.
template<int BNT,int BIAS,int GELU,int RES,int OMODE,int SPLITK>
__global__ __launch_bounds__(256,2) void gemm_bt(const unsigned short* __restrict__ A,
    const unsigned short* __restrict__ Bt, const float* __restrict__ bias,
    const float* __restrict__ resid, float* __restrict__ outF,
    unsigned short* __restrict__ outB, unsigned short* __restrict__ outK,
    unsigned short* __restrict__ outV, int M, int Nn, int K)
{
  constexpr int MI  = (BNT==128) ? 4 : 2;
  constexpr int BCH = (BNT==128) ? 4 : 2;
  constexpr int ABYTES = 128*64*2;
  constexpr int BBYTES = BNT*64*2;
  __shared__ __align__(16) char lds[2*ABYTES + 2*BBYTES];
  const int tid = threadIdx.x;
  const int w = tid >> 6, lane = tid & 63;
  const int quad = lane >> 4, l16 = lane & 15;
  const unsigned Wid = xcd_chunk(blockIdx.y*gridDim.x + blockIdx.x,
                                 gridDim.x*gridDim.y);
  const int bx = Wid % gridDim.x, by = Wid / gridDim.x;
  const int m0 = by*128, n0 = bx*BNT;
  const int wm = (BNT==128) ? (w >> 1)*64 : w*32;
  const int wn = (BNT==128) ? (w & 1)*64 : 0;
  const int srow = lane >> 3, sslot = lane & 7;
  f32x4 acc[MI][4] = {};
  const int kseg = SPLITK > 1 ? K / SPLITK : K;
  const int kBeg = SPLITK > 1 ? blockIdx.z * kseg : 0;
  const int nsteps = kseg >> 6;

  auto STAGE = [&](int buf, int k0){
    char* Ad = lds + buf*ABYTES;
    char* Bd = lds + 2*ABYTES + buf*BBYTES;
    #pragma unroll
    for (int i = 0; i < 4; i++){
      const int rb = (w*4 + i)*8;
      const int r = rb + srow;
      const int c = sslot ^ (r & 7);
      gl2lds16(A + (size_t)(m0 + r)*K + k0 + c*8, Ad + rb*128);
    }
    #pragma unroll
    for (int i = 0; i < BCH; i++){
      const int rb = (w*BCH + i)*8;
      const int r = rb + srow;
      const int c = sslot ^ (r & 7);
      gl2lds16(Bt + (size_t)(n0 + r)*K + k0 + c*8, Bd + rb*128);
    }
  };

  STAGE(0, kBeg);
  __syncthreads();
  for (int t = 0; t < nsteps; t++){
    const int cur = t & 1;
    if (t + 1 < nsteps) STAGE(cur ^ 1, kBeg + (t+1)*64);
    const unsigned short* Ac = (const unsigned short*)(lds + cur*ABYTES);
    const unsigned short* Bc = (const unsigned short*)(lds + 2*ABYTES + cur*BBYTES);
    #pragma unroll
    for (int kc = 0; kc < 2; kc++){
      bf16x8 af[MI], bfr[4];
      #pragma unroll
      for (int mi = 0; mi < MI; mi++){
        const int r = wm + mi*16 + l16;
        af[mi] = *(const bf16x8*)(Ac + r*64 + (((kc*4 + quad) ^ (r & 7))*8));
      }
      #pragma unroll
      for (int nj = 0; nj < 4; nj++){
        const int r = wn + nj*16 + l16;
        bfr[nj] = *(const bf16x8*)(Bc + r*64 + (((kc*4 + quad) ^ (r & 7))*8));
      }
      #pragma unroll
      for (int mi = 0; mi < MI; mi++)
        #pragma unroll
        for (int nj = 0; nj < 4; nj++)
          acc[mi][nj] = MFMA16(af[mi], bfr[nj], acc[mi][nj]);
    }
    __syncthreads();
  }

  #pragma unroll
  for (int nj = 0; nj < 4; nj++){
    const int col = n0 + wn + nj*16 + l16;
    const float bv = BIAS ? bias[col] : 0.f;
    #pragma unroll
    for (int mi = 0; mi < MI; mi++){
      #pragma unroll
      for (int r = 0; r < 4; r++){
        const int row = m0 + wm + mi*16 + quad*4 + r;
        float v = acc[mi][nj][r];
        if (SPLITK > 1){
          if (blockIdx.z == 0){
            if (BIAS) v += bias[col];
            if (RES)  v += resid[(size_t)row*Nn + col];
          }
          atomicAdd(&outF[(size_t)row*Nn + col], v);
          continue;
        }
        v += bv;
        if (GELU) v = 0.5f*v*(1.f + erff(v*0.70710678118654752f));
        if (RES)  v += resid[(size_t)row*Nn + col];
        if (OMODE == 0) outF[(size_t)row*Nn + col] = v;
        else outB[(size_t)row*Nn + col] = f2b(v);
      }
    }
  }
}

// ---------------- fused attention, no-max softmax (scores tiny; log2e folded into Wq)
// q,k token-major bf16; vt [bh][d][kv-pi-permuted] bf16.
// Block = one (b,h) x 128 Q rows; 4 waves = (wq: q-half of 64 rows) x (wk: kv-half).
// Grid XCD-chunk-swizzled: each XCD owns 4 heads (2MB K+V, L2-resident).
__global__ __launch_bounds__(256,2) void attn_kernel(const unsigned short* __restrict__ q,
    const unsigned short* __restrict__ k, const unsigned short* __restrict__ vt,
    unsigned short* __restrict__ y)
{
  __shared__ __align__(16) unsigned short Kl[2][64*64];
  __shared__ __align__(16) unsigned short Vl[2][64*64];
  __shared__ __align__(16) unsigned short Pp[4][64*68];
  const int tid = threadIdx.x;
  const int w = tid >> 6, lane = tid & 63;
  const int wq = w & 1, wk = w >> 1;
  const int quad = lane >> 4, l16 = lane & 15;
  const unsigned Wid = xcd_chunk(blockIdx.y*gridDim.x + blockIdx.x,
                                 gridDim.x*gridDim.y);
  const int qt = Wid & 15, bh = Wid >> 4;
  const int b = bh >> 4, h = bh & 15;
  const size_t tb  = ((size_t)b*SEQ)*CH + h*HD;
  const size_t vb_ = (size_t)bh*HD*SEQ;
  const int qr0 = qt*128 + wq*64;

  bf16x8 qf[4][2];
  #pragma unroll
  for (int mi = 0; mi < 4; mi++)
    #pragma unroll
    for (int kc = 0; kc < 2; kc++)
      qf[mi][kc] = *(const bf16x8*)(q + tb + (size_t)(qr0 + mi*16 + l16)*CH + kc*32 + quad*8);

  float sacc[4][4];
  f32x4 o[4][4] = {};
  #pragma unroll
  for (int mi = 0; mi < 4; mi++)
    #pragma unroll
    for (int r = 0; r < 4; r++) sacc[mi][r] = 0.f;

  for (int t = 0; t < 16; t++){
    const int kv0 = wk*1024 + t*64;
    __syncthreads();
    #pragma unroll
    for (int i = 0; i < 8; i++){
      const int r = i*8 + (lane >> 3);
      const int c = (lane & 7) ^ (r & 7);
      if (wq == 0)
        gl2lds16(k  + tb  + (size_t)(kv0 + r)*CH + c*8, (char*)&Kl[wk][0] + i*1024);
      else
        gl2lds16(vt + vb_ + (size_t)r*SEQ + kv0 + c*8, (char*)&Vl[wk][0] + i*1024);
    }
    __syncthreads();

    f32x4 s[4][4] = {};
    #pragma unroll
    for (int kc = 0; kc < 2; kc++){
      #pragma unroll
      for (int nj = 0; nj < 4; nj++){
        bf16x8 kf = *(const bf16x8*)(&Kl[wk][0] + (nj*16 + l16)*64 + (((kc*4 + quad) ^ (l16 & 7))*8));
        #pragma unroll
        for (int mi = 0; mi < 4; mi++)
          s[mi][nj] = MFMA16(qf[mi][kc], kf, s[mi][nj]);
      }
    }
    #pragma unroll
    for (int mi = 0; mi < 4; mi++){
      #pragma unroll
      for (int r = 0; r < 4; r++){
        const float p0 = fexp2(s[mi][0][r]);
        const float p1 = fexp2(s[mi][1][r]);
        const float p2 = fexp2(s[mi][2][r]);
        const float p3 = fexp2(s[mi][3][r]);
        sacc[mi][r] += (p0 + p1) + (p2 + p3);
        uint2 pk;
        pk.x = pk2(p0, p1);
        pk.y = pk2(p2, p3);
        const int prow = mi*16 + quad*4 + r;
        *(uint2*)(&Pp[w][prow*68 + l16*4]) = pk;
      }
    }
    #pragma unroll
    for (int kc = 0; kc < 2; kc++){
      bf16x8 pa[4];
      #pragma unroll
      for (int mi = 0; mi < 4; mi++)
        pa[mi] = *(const bf16x8*)(&Pp[w][(mi*16 + l16)*68 + kc*32 + quad*8]);
      #pragma unroll
      for (int nd = 0; nd < 4; nd++){
        bf16x8 vf = *(const bf16x8*)(&Vl[wk][0] + (nd*16 + l16)*64 + (((kc*4 + quad) ^ (l16 & 7))*8));
        #pragma unroll
        for (int mi = 0; mi < 4; mi++)
          o[mi][nd] = MFMA16(pa[mi], vf, o[mi][nd]);
      }
    }
  }

  __syncthreads();
  float* ob = wq ? (float*)&Vl[0][0] : (float*)&Kl[0][0];
  float* sb = (float*)&Pp[2 + wq][0];
  if (wk == 1){
    #pragma unroll
    for (int mi = 0; mi < 4; mi++)
      #pragma unroll
      for (int nd = 0; nd < 4; nd++)
        #pragma unroll
        for (int r = 0; r < 4; r++){
          const int idx = (mi*4 + nd)*4 + r;
          ob[lane*64 + ((idx + lane) & 63)] = o[mi][nd][r];
        }
    #pragma unroll
    for (int mi = 0; mi < 4; mi++)
      #pragma unroll
      for (int r = 0; r < 4; r++)
        sb[lane*16 + ((mi*4 + r + lane) & 15)] = sacc[mi][r];
  }
  __syncthreads();
  if (wk == 0){
    #pragma unroll
    for (int mi = 0; mi < 4; mi++)
      #pragma unroll
      for (int nd = 0; nd < 4; nd++)
        #pragma unroll
        for (int r = 0; r < 4; r++){
          const int idx = (mi*4 + nd)*4 + r;
          o[mi][nd][r] += ob[lane*64 + ((idx + lane) & 63)];
        }
    #pragma unroll
    for (int mi = 0; mi < 4; mi++){
      #pragma unroll
      for (int r = 0; r < 4; r++){
        float sum = sacc[mi][r] + sb[lane*16 + ((mi*4 + r + lane) & 15)];
        #pragma unroll
        for (int off = 1; off < 16; off <<= 1) sum += __shfl_xor(sum, off, 64);
        const float inv = 1.f / sum;
        const int qr = qr0 + mi*16 + quad*4 + r;
        #pragma unroll
        for (int nd = 0; nd < 4; nd++)
          y[tb + (size_t)qr*CH + nd*16 + l16] = f2b(o[mi][nd][r]*inv);
      }
    }
  }
}

extern "C" void kernel_launch(void* const* d_in, const int* in_sizes, int n_in,
                              void* d_out, int out_size, void* d_ws, size_t ws_size,
                              hipStream_t stream)
{
  (void)in_sizes; (void)n_in; (void)out_size; (void)ws_size;
  const float* x   = (const float*)d_in[0];
  const float* Wq  = (const float*)d_in[1];
  const float* Wk  = (const float*)d_in[2];
  const float* Wv  = (const float*)d_in[3];
  const float* Wp  = (const float*)d_in[4];
  const float* bp  = (const float*)d_in[5];
  const float* W1  = (const float*)d_in[6];
  const float* b1  = (const float*)d_in[7];
  const float* W2  = (const float*)d_in[8];
  const float* b2  = (const float*)d_in[9];
  const float* g1  = (const float*)d_in[10];
  const float* be1 = (const float*)d_in[11];
  const float* g2  = (const float*)d_in[12];
  const float* be2 = (const float*)d_in[13];
  float* out = (float*)d_out;
  char* ws = (char*)d_ws;
  const size_t MB = 1024*1024;
  unsigned short* wq_t = (unsigned short*)(ws +  0*MB);  // stacked QKV^T: rows 0..3071
  unsigned short* wk_t = (unsigned short*)(ws +  2*MB);
  unsigned short* wv_t = (unsigned short*)(ws +  4*MB);
  unsigned short* wp_t = (unsigned short*)(ws +  6*MB);
  unsigned short* w1_t = (unsigned short*)(ws +  8*MB);
  unsigned short* w2_t = (unsigned short*)(ws + 16*MB);
  unsigned short* xn   = (unsigned short*)(ws + 24*MB);
  unsigned short* qb   = (unsigned short*)(ws + 32*MB);
  unsigned short* kb   = (unsigned short*)(ws + 40*MB);
  unsigned short* vtb  = (unsigned short*)(ws + 48*MB);
  unsigned short* yb   = (unsigned short*)(ws + 56*MB);
  float*          x2   = (float*)         (ws + 64*MB);
  unsigned short* xn2  = (unsigned short*)(ws + 80*MB);
  unsigned short* hb   = (unsigned short*)(ws + 88*MB);

  // weight transposes to B^T bf16 (head scale * log2e folded into Wq)
  transpose_cvt<<<dim3(16,16),256,0,stream>>>(Wq, wq_t, CH, CH, 0.18033688011112042f);
  transpose_cvt<<<dim3(16,16),256,0,stream>>>(Wk, wk_t, CH, CH, 1.f);
  transpose_cvt<<<dim3(16,16),256,0,stream>>>(Wv, wv_t, CH, CH, 1.f);
  transpose_cvt<<<dim3(16,16),256,0,stream>>>(Wp, wp_t, CH, CH, 1.f);
  transpose_cvt<<<dim3(64,16),256,0,stream>>>(W1, w1_t, CH, FF, 1.f);
  transpose_cvt<<<dim3(16,64),256,0,stream>>>(W2, w2_t, FF, CH, 1.f);

  ln_kernel<<<BN,256,0,stream>>>(x, g1, be1, xn);
  // fused QKV: Bt = stacked [3072][1024] starting at wq_t
  gemm256<0,0,0,3,0><<<dim3(12,16),512,0,stream>>>(xn, wq_t, nullptr, nullptr,
      nullptr, qb, kb, vtb, BN, 3072, CH);
  attn_kernel<<<dim3(16,32),256,0,stream>>>(qb, kb, vtb, yb);
  gemm_bt<64,1,0,1,0,0><<<dim3(16,32),256,0,stream>>>(yb, wp_t, bp, x, x2,
      nullptr, nullptr, nullptr, BN, CH, CH);
  ln_kernel<<<BN,256,0,stream>>>(x2, g2, be2, xn2);
  gemm256<1,1,0,1,0><<<dim3(16,16),512,0,stream>>>(xn2, w1_t, b1, nullptr, nullptr,
      hb, nullptr, nullptr, BN, FF, CH);
  // W2: split-K x4 at 256^2 tile (fills all CUs at N=1024); atomics into out
  hipMemsetAsync(out, 0, (size_t)BN*CH*sizeof(float), stream);
  gemm256<1,0,1,0,4><<<dim3(4,16,4),512,0,stream>>>(hb, w2_t, b2, x2, out,
      nullptr, nullptr, nullptr, BN, CH, FF);
}

// Round 4
// 343.703 us; speedup vs baseline: 1.1913x; 1.1913x over previous
//
#include <hip/hip_runtime.h>
#include <math.h>

// Problem constants (B=2, N=2048, C=1024, F=4096, H=16, D=64)
#define BN  4096
#define SEQ 2048
#define CH  1024
#define FF  4096
#define NH  16
#define HD  64

typedef short bf16x8 __attribute__((ext_vector_type(8)));
typedef float f32x4  __attribute__((ext_vector_type(4)));

#define MFMA16(a,b,c) __builtin_amdgcn_mfma_f32_16x16x32_bf16(a,b,c,0,0,0)

__device__ __forceinline__ unsigned short f2b(float f){
  unsigned u = __float_as_uint(f);
  u += 0x7fffu + ((u>>16)&1u);          // RNE to bf16
  return (unsigned short)(u>>16);
}

// pack two fp32 -> two bf16 (truncation) in ONE v_perm_b32
__device__ __forceinline__ unsigned pk2(float a, float b){
  return __builtin_amdgcn_perm(__float_as_uint(b), __float_as_uint(a), 0x07060302u);
}

#if __has_builtin(__builtin_amdgcn_exp2f)
__device__ __forceinline__ float fexp2(float x){ return __builtin_amdgcn_exp2f(x); }
#else
__device__ __forceinline__ float fexp2(float x){
  float r; asm("v_exp_f32 %0, %1" : "=v"(r) : "v"(x)); return r;
}
#endif

__device__ __forceinline__ void gl2lds16(const void* g, void* l){
  __builtin_amdgcn_global_load_lds(
      (__attribute__((address_space(1))) void*)g,
      (__attribute__((address_space(3))) void*)l, 16, 0, 0);
}

// bijective chunked XCD swizzle (T1): blocks with dispatch id d land on XCD
// d%8; remap so each XCD processes a CONTIGUOUS chunk of logical work ids.
// Requires nwg % 8 == 0 (all our grids satisfy this).
__device__ __forceinline__ unsigned xcd_chunk(unsigned id, unsigned nwg){
  const unsigned cpx = nwg >> 3;
  return (id & 7u)*cpx + (id >> 3);
}

// ---------------- transpose + fp32->bf16 convert (out[s][r] = in[r][s]*scale)
__global__ __launch_bounds__(256) void transpose_cvt(const float* __restrict__ in,
    unsigned short* __restrict__ out, int R, int S, float scale)
{
  __shared__ float tile[64][65];
  const int tid = threadIdx.x;
  const int tx = tid & 63, ty = tid >> 6;
  const int s0 = blockIdx.x * 64, r0 = blockIdx.y * 64;
  #pragma unroll
  for (int j = 0; j < 16; j++){
    int r = ty + j*4;
    tile[r][tx] = in[(size_t)(r0 + r)*S + s0 + tx];
  }
  __syncthreads();
  #pragma unroll
  for (int j = 0; j < 16; j++){
    int s = ty + j*4;
    out[(size_t)(s0 + s)*R + r0 + tx] = f2b(tile[tx][s] * scale);
  }
}

// ---------------- LayerNorm (fp32 in, bf16 out), one block per row of 1024
__global__ __launch_bounds__(256) void ln_kernel(const float* __restrict__ x,
    const float* __restrict__ gamma, const float* __restrict__ beta,
    unsigned short* __restrict__ out)
{
  const int row = blockIdx.x, tid = threadIdx.x;
  const float4 xv = ((const float4*)(x + (size_t)row*CH))[tid];
  float s  = xv.x + xv.y + xv.z + xv.w;
  float ss = xv.x*xv.x + xv.y*xv.y + xv.z*xv.z + xv.w*xv.w;
  #pragma unroll
  for (int off = 1; off < 64; off <<= 1){
    s  += __shfl_xor(s,  off, 64);
    ss += __shfl_xor(ss, off, 64);
  }
  __shared__ float red[8];
  const int w = tid >> 6;
  if ((tid & 63) == 0){ red[w] = s; red[4+w] = ss; }
  __syncthreads();
  s  = red[0]+red[1]+red[2]+red[3];
  ss = red[4]+red[5]+red[6]+red[7];
  const float mu   = s * (1.f/CH);
  const float rstd = rsqrtf(ss*(1.f/CH) - mu*mu + 1e-6f);
  const float4 g = ((const float4*)gamma)[tid];
  const float4 b = ((const float4*)beta )[tid];
  ushort4 o;
  o.x = f2b((xv.x-mu)*rstd*g.x + b.x);
  o.y = f2b((xv.y-mu)*rstd*g.y + b.y);
  o.z = f2b((xv.z-mu)*rstd*g.z + b.z);
  o.w = f2b((xv.w-mu)*rstd*g.w + b.w);
  ((ushort4*)(out + (size_t)row*CH))[tid] = o;
}

// ---------------- gemm128: 128x128 tile, BK=32, dbuf LDS = 32KB -> 4 blocks/CU.
// 2-phase loop (STAGE next buf; ds_read+MFMA cur; ONE __syncthreads) — the
// vmcnt(0) drain at the barrier hides under the 3 other resident blocks.
// Swizzle for 64B rows: slot s of row r holds global 16B chunk s^((r>>1)&3);
// ds_read_b128 by 16 consecutive rows then covers each bank exactly 2x (free).
// Staging pointers strength-reduced (advance 64B/iter, no 64-bit rebuild).
// OMODE: 0 = fp32 out, 1 = bf16 out, 3 = fused QKV epilogue (q/k token-major,
// v pi-permuted transposed). OMODE 1/3 stage wave's 64x64 bf16 tile in LDS
// scratch then store coalesced 16B.
template<int BIAS,int GELU,int RES,int OMODE>
__global__ __launch_bounds__(256,4) void gemm128(const unsigned short* __restrict__ A,
    const unsigned short* __restrict__ Bt, const float* __restrict__ bias,
    const float* __restrict__ resid, float* __restrict__ outF,
    unsigned short* __restrict__ outB, unsigned short* __restrict__ outK,
    unsigned short* __restrict__ outV, int M, int Nn, int K)
{
  __shared__ __align__(16) char lds[32768];   // A dbuf 2x8KB @0 | B dbuf 2x8KB @16K
  const int tid = threadIdx.x;
  const int w = tid >> 6, lane = tid & 63;
  const int quad = lane >> 4, l16 = lane & 15;
  const unsigned Wid = xcd_chunk(blockIdx.y*gridDim.x + blockIdx.x,
                                 gridDim.x*gridDim.y);
  const int bx = Wid % gridDim.x, by = Wid / gridDim.x;
  const int m0 = by*128, n0 = bx*128;
  const int wm = (w >> 1)*64, wn = (w & 1)*64;
  f32x4 acc[4][4] = {};
  const int nt = K >> 5;

  // staging: 8 chunks of 1KB per operand per buffer; this thread owns chunks
  // {w*2, w*2+1}. lane l -> row ci*16 + (l>>2), slot l&3, global chunk
  // g = (l&3) ^ ((row>>1)&3).
  const int ci0 = w*2, ci1 = w*2 + 1;
  const int ra0 = ci0*16 + (lane >> 2);
  const int ra1 = ra0 + 16;
  const int ga0 = (lane & 3) ^ ((ra0 >> 1) & 3);
  const int ga1 = (lane & 3) ^ ((ra1 >> 1) & 3);
  const unsigned short* aS0 = A  + (size_t)(m0 + ra0)*K + ga0*8;
  const unsigned short* aS1 = A  + (size_t)(m0 + ra1)*K + ga1*8;
  const unsigned short* bS0 = Bt + (size_t)(n0 + ra0)*K + ga0*8;
  const unsigned short* bS1 = Bt + (size_t)(n0 + ra1)*K + ga1*8;

  auto STAGE = [&](int buf){
    char* Ad = lds + buf*8192;
    char* Bd = lds + 16384 + buf*8192;
    gl2lds16(aS0, Ad + ci0*1024);
    gl2lds16(aS1, Ad + ci1*1024);
    gl2lds16(bS0, Bd + ci0*1024);
    gl2lds16(bS1, Bd + ci1*1024);
    aS0 += 32; aS1 += 32; bS0 += 32; bS1 += 32;
  };

  STAGE(0);
  __syncthreads();
  for (int t = 0; t < nt; t++){
    const int cur = t & 1;
    if (t + 1 < nt) STAGE(cur ^ 1);
    const unsigned short* Ac = (const unsigned short*)(lds + cur*8192);
    const unsigned short* Bc = (const unsigned short*)(lds + 16384 + cur*8192);
    bf16x8 af[4], bfr[4];
    #pragma unroll
    for (int mi = 0; mi < 4; mi++){
      const int r = wm + mi*16 + l16;
      af[mi] = *(const bf16x8*)(Ac + r*32 + ((quad ^ ((r >> 1) & 3))*8));
    }
    #pragma unroll
    for (int nj = 0; nj < 4; nj++){
      const int r = wn + nj*16 + l16;
      bfr[nj] = *(const bf16x8*)(Bc + r*32 + ((quad ^ ((r >> 1) & 3))*8));
    }
    #pragma unroll
    for (int mi = 0; mi < 4; mi++)
      #pragma unroll
      for (int nj = 0; nj < 4; nj++)
        acc[mi][nj] = MFMA16(af[mi], bfr[nj], acc[mi][nj]);
    __syncthreads();
  }

  // epilogue: C/D layout col = l16, row = quad*4 + reg
  const int colb = n0 + wn;          // 64-aligned
  const int row0 = m0 + wm;          // 64-aligned
  if (OMODE == 1 || OMODE == 3){
    unsigned short* scr = (unsigned short*)lds + w*4096;   // 8KB per wave
    const int cg = (OMODE == 3) ? (colb >> 10) : 0;
    #pragma unroll
    for (int nj = 0; nj < 4; nj++){
      const int col = colb + nj*16 + l16;
      const float bv = BIAS ? bias[col] : 0.f;
      #pragma unroll
      for (int mi = 0; mi < 4; mi++){
        #pragma unroll
        for (int r = 0; r < 4; r++){
          const int rl = mi*16 + quad*4 + r;     // local row 0..63
          float v = acc[mi][nj][r] + bv;
          if (GELU) v = 0.5f*v*(1.f + erff(v*0.70710678118654752f));
          if (RES)  v += resid[(size_t)(row0 + rl)*Nn + col];
          const unsigned short b16 = f2b(v);
          if (OMODE == 3 && cg == 2){
            // V: scratch [64 d][64 tok], tokens pi-permuted
            const int d = nj*16 + l16;
            scr[d*64 + (((rl & 15) << 2) | (rl >> 4))] = b16;
          } else {
            scr[rl*64 + nj*16 + l16] = b16;
          }
        }
      }
    }
    const int sl = (lane & 7)*8;
    #pragma unroll
    for (int j = 0; j < 8; j++){
      const int rr = j*8 + (lane >> 3);
      const bf16x8 vv = *(const bf16x8*)(scr + rr*64 + sl);
      if (OMODE == 1){
        *(bf16x8*)(outB + (size_t)(row0 + rr)*Nn + colb + sl) = vv;
      } else {
        if (cg == 0)
          *(bf16x8*)(outB + (size_t)(row0 + rr)*CH + (colb & (CH-1)) + sl) = vv;
        else if (cg == 1)
          *(bf16x8*)(outK + (size_t)(row0 + rr)*CH + (colb & (CH-1)) + sl) = vv;
        else {
          const int bb = row0 >> 11;
          const int hh = (colb & (CH-1)) >> 6;
          *(bf16x8*)(outV + ((size_t)((bb*NH + hh)*HD) + rr)*SEQ
                          + (row0 & (SEQ-1)) + sl) = vv;
        }
      }
    }
    return;
  }
  // OMODE 0: fp32 direct
  #pragma unroll
  for (int nj = 0; nj < 4; nj++){
    const int col = colb + nj*16 + l16;
    const float bv = BIAS ? bias[col] : 0.f;
    #pragma unroll
    for (int mi = 0; mi < 4; mi++){
      #pragma unroll
      for (int r = 0; r < 4; r++){
        const int row = row0 + mi*16 + quad*4 + r;
        float v = acc[mi][nj][r] + bv;
        if (GELU) v = 0.5f*v*(1.f + erff(v*0.70710678118654752f));
        if (RES)  v += resid[(size_t)row*Nn + col];
        outF[(size_t)row*Nn + col] = v;
      }
    }
  }
}

// ---------------- 128-row-tile GEMM, BK=64 dbuf (proven R2 config; Wp + W2)
template<int BNT,int BIAS,int GELU,int RES,int OMODE,int SPLITK>
__global__ __launch_bounds__(256,2) void gemm_bt(const unsigned short* __restrict__ A,
    const unsigned short* __restrict__ Bt, const float* __restrict__ bias,
    const float* __restrict__ resid, float* __restrict__ outF,
    unsigned short* __restrict__ outB, unsigned short* __restrict__ outK,
    unsigned short* __restrict__ outV, int M, int Nn, int K)
{
  constexpr int MI  = (BNT==128) ? 4 : 2;
  constexpr int BCH = (BNT==128) ? 4 : 2;
  constexpr int ABYTES = 128*64*2;
  constexpr int BBYTES = BNT*64*2;
  __shared__ __align__(16) char lds[2*ABYTES + 2*BBYTES];
  const int tid = threadIdx.x;
  const int w = tid >> 6, lane = tid & 63;
  const int quad = lane >> 4, l16 = lane & 15;
  const unsigned Wid = xcd_chunk(blockIdx.y*gridDim.x + blockIdx.x,
                                 gridDim.x*gridDim.y);
  const int bx = Wid % gridDim.x, by = Wid / gridDim.x;
  const int m0 = by*128, n0 = bx*BNT;
  const int wm = (BNT==128) ? (w >> 1)*64 : w*32;
  const int wn = (BNT==128) ? (w & 1)*64 : 0;
  const int srow = lane >> 3, sslot = lane & 7;
  f32x4 acc[MI][4] = {};
  const int kseg = SPLITK > 1 ? K / SPLITK : K;
  const int kBeg = SPLITK > 1 ? blockIdx.z * kseg : 0;
  const int nsteps = kseg >> 6;

  auto STAGE = [&](int buf, int k0){
    char* Ad = lds + buf*ABYTES;
    char* Bd = lds + 2*ABYTES + buf*BBYTES;
    #pragma unroll
    for (int i = 0; i < 4; i++){
      const int rb = (w*4 + i)*8;
      const int r = rb + srow;
      const int c = sslot ^ (r & 7);
      gl2lds16(A + (size_t)(m0 + r)*K + k0 + c*8, Ad + rb*128);
    }
    #pragma unroll
    for (int i = 0; i < BCH; i++){
      const int rb = (w*BCH + i)*8;
      const int r = rb + srow;
      const int c = sslot ^ (r & 7);
      gl2lds16(Bt + (size_t)(n0 + r)*K + k0 + c*8, Bd + rb*128);
    }
  };

  STAGE(0, kBeg);
  __syncthreads();
  for (int t = 0; t < nsteps; t++){
    const int cur = t & 1;
    if (t + 1 < nsteps) STAGE(cur ^ 1, kBeg + (t+1)*64);
    const unsigned short* Ac = (const unsigned short*)(lds + cur*ABYTES);
    const unsigned short* Bc = (const unsigned short*)(lds + 2*ABYTES + cur*BBYTES);
    #pragma unroll
    for (int kc = 0; kc < 2; kc++){
      bf16x8 af[MI], bfr[4];
      #pragma unroll
      for (int mi = 0; mi < MI; mi++){
        const int r = wm + mi*16 + l16;
        af[mi] = *(const bf16x8*)(Ac + r*64 + (((kc*4 + quad) ^ (r & 7))*8));
      }
      #pragma unroll
      for (int nj = 0; nj < 4; nj++){
        const int r = wn + nj*16 + l16;
        bfr[nj] = *(const bf16x8*)(Bc + r*64 + (((kc*4 + quad) ^ (r & 7))*8));
      }
      #pragma unroll
      for (int mi = 0; mi < MI; mi++)
        #pragma unroll
        for (int nj = 0; nj < 4; nj++)
          acc[mi][nj] = MFMA16(af[mi], bfr[nj], acc[mi][nj]);
    }
    __syncthreads();
  }

  #pragma unroll
  for (int nj = 0; nj < 4; nj++){
    const int col = n0 + wn + nj*16 + l16;
    const float bv = BIAS ? bias[col] : 0.f;
    #pragma unroll
    for (int mi = 0; mi < MI; mi++){
      #pragma unroll
      for (int r = 0; r < 4; r++){
        const int row = m0 + wm + mi*16 + quad*4 + r;
        float v = acc[mi][nj][r];
        if (SPLITK > 1){
          if (blockIdx.z == 0){
            if (BIAS) v += bias[col];
            if (RES)  v += resid[(size_t)row*Nn + col];
          }
          atomicAdd(&outF[(size_t)row*Nn + col], v);
          continue;
        }
        v += bv;
        if (GELU) v = 0.5f*v*(1.f + erff(v*0.70710678118654752f));
        if (RES)  v += resid[(size_t)row*Nn + col];
        if (OMODE == 0) outF[(size_t)row*Nn + col] = v;
        else outB[(size_t)row*Nn + col] = f2b(v);
      }
    }
  }
}

// ---------------- fused attention, no-max softmax (scores tiny; log2e folded into Wq)
// q,k token-major bf16; vt [bh][d][kv-pi-permuted] bf16.
// Block = one (b,h) x 128 Q rows; 4 waves = (wq: q-half of 64 rows) x (wk: kv-half).
// Grid XCD-chunk-swizzled: each XCD owns 4 heads (2MB K+V, L2-resident).
__global__ __launch_bounds__(256,2) void attn_kernel(const unsigned short* __restrict__ q,
    const unsigned short* __restrict__ k, const unsigned short* __restrict__ vt,
    unsigned short* __restrict__ y)
{
  __shared__ __align__(16) unsigned short Kl[2][64*64];
  __shared__ __align__(16) unsigned short Vl[2][64*64];
  __shared__ __align__(16) unsigned short Pp[4][64*68];
  const int tid = threadIdx.x;
  const int w = tid >> 6, lane = tid & 63;
  const int wq = w & 1, wk = w >> 1;
  const int quad = lane >> 4, l16 = lane & 15;
  const unsigned Wid = xcd_chunk(blockIdx.y*gridDim.x + blockIdx.x,
                                 gridDim.x*gridDim.y);
  const int qt = Wid & 15, bh = Wid >> 4;
  const int b = bh >> 4, h = bh & 15;
  const size_t tb  = ((size_t)b*SEQ)*CH + h*HD;
  const size_t vb_ = (size_t)bh*HD*SEQ;
  const int qr0 = qt*128 + wq*64;

  bf16x8 qf[4][2];
  #pragma unroll
  for (int mi = 0; mi < 4; mi++)
    #pragma unroll
    for (int kc = 0; kc < 2; kc++)
      qf[mi][kc] = *(const bf16x8*)(q + tb + (size_t)(qr0 + mi*16 + l16)*CH + kc*32 + quad*8);

  float sacc[4][4];
  f32x4 o[4][4] = {};
  #pragma unroll
  for (int mi = 0; mi < 4; mi++)
    #pragma unroll
    for (int r = 0; r < 4; r++) sacc[mi][r] = 0.f;

  for (int t = 0; t < 16; t++){
    const int kv0 = wk*1024 + t*64;
    __syncthreads();
    #pragma unroll
    for (int i = 0; i < 8; i++){
      const int r = i*8 + (lane >> 3);
      const int c = (lane & 7) ^ (r & 7);
      if (wq == 0)
        gl2lds16(k  + tb  + (size_t)(kv0 + r)*CH + c*8, (char*)&Kl[wk][0] + i*1024);
      else
        gl2lds16(vt + vb_ + (size_t)r*SEQ + kv0 + c*8, (char*)&Vl[wk][0] + i*1024);
    }
    __syncthreads();

    f32x4 s[4][4] = {};
    #pragma unroll
    for (int kc = 0; kc < 2; kc++){
      #pragma unroll
      for (int nj = 0; nj < 4; nj++){
        bf16x8 kf = *(const bf16x8*)(&Kl[wk][0] + (nj*16 + l16)*64 + (((kc*4 + quad) ^ (l16 & 7))*8));
        #pragma unroll
        for (int mi = 0; mi < 4; mi++)
          s[mi][nj] = MFMA16(qf[mi][kc], kf, s[mi][nj]);
      }
    }
    #pragma unroll
    for (int mi = 0; mi < 4; mi++){
      #pragma unroll
      for (int r = 0; r < 4; r++){
        const float p0 = fexp2(s[mi][0][r]);
        const float p1 = fexp2(s[mi][1][r]);
        const float p2 = fexp2(s[mi][2][r]);
        const float p3 = fexp2(s[mi][3][r]);
        sacc[mi][r] += (p0 + p1) + (p2 + p3);
        uint2 pk;
        pk.x = pk2(p0, p1);
        pk.y = pk2(p2, p3);
        const int prow = mi*16 + quad*4 + r;
        *(uint2*)(&Pp[w][prow*68 + l16*4]) = pk;
      }
    }
    #pragma unroll
    for (int kc = 0; kc < 2; kc++){
      bf16x8 pa[4];
      #pragma unroll
      for (int mi = 0; mi < 4; mi++)
        pa[mi] = *(const bf16x8*)(&Pp[w][(mi*16 + l16)*68 + kc*32 + quad*8]);
      #pragma unroll
      for (int nd = 0; nd < 4; nd++){
        bf16x8 vf = *(const bf16x8*)(&Vl[wk][0] + (nd*16 + l16)*64 + (((kc*4 + quad) ^ (l16 & 7))*8));
        #pragma unroll
        for (int mi = 0; mi < 4; mi++)
          o[mi][nd] = MFMA16(pa[mi], vf, o[mi][nd]);
      }
    }
  }

  __syncthreads();
  float* ob = wq ? (float*)&Vl[0][0] : (float*)&Kl[0][0];
  float* sb = (float*)&Pp[2 + wq][0];
  if (wk == 1){
    #pragma unroll
    for (int mi = 0; mi < 4; mi++)
      #pragma unroll
      for (int nd = 0; nd < 4; nd++)
        #pragma unroll
        for (int r = 0; r < 4; r++){
          const int idx = (mi*4 + nd)*4 + r;
          ob[lane*64 + ((idx + lane) & 63)] = o[mi][nd][r];
        }
    #pragma unroll
    for (int mi = 0; mi < 4; mi++)
      #pragma unroll
      for (int r = 0; r < 4; r++)
        sb[lane*16 + ((mi*4 + r + lane) & 15)] = sacc[mi][r];
  }
  __syncthreads();
  if (wk == 0){
    #pragma unroll
    for (int mi = 0; mi < 4; mi++)
      #pragma unroll
      for (int nd = 0; nd < 4; nd++)
        #pragma unroll
        for (int r = 0; r < 4; r++){
          const int idx = (mi*4 + nd)*4 + r;
          o[mi][nd][r] += ob[lane*64 + ((idx + lane) & 63)];
        }
    #pragma unroll
    for (int mi = 0; mi < 4; mi++){
      #pragma unroll
      for (int r = 0; r < 4; r++){
        float sum = sacc[mi][r] + sb[lane*16 + ((mi*4 + r + lane) & 15)];
        #pragma unroll
        for (int off = 1; off < 16; off <<= 1) sum += __shfl_xor(sum, off, 64);
        const float inv = 1.f / sum;
        const int qr = qr0 + mi*16 + quad*4 + r;
        #pragma unroll
        for (int nd = 0; nd < 4; nd++)
          y[tb + (size_t)qr*CH + nd*16 + l16] = f2b(o[mi][nd][r]*inv);
      }
    }
  }
}

extern "C" void kernel_launch(void* const* d_in, const int* in_sizes, int n_in,
                              void* d_out, int out_size, void* d_ws, size_t ws_size,
                              hipStream_t stream)
{
  (void)in_sizes; (void)n_in; (void)out_size; (void)ws_size;
  const float* x   = (const float*)d_in[0];
  const float* Wq  = (const float*)d_in[1];
  const float* Wk  = (const float*)d_in[2];
  const float* Wv  = (const float*)d_in[3];
  const float* Wp  = (const float*)d_in[4];
  const float* bp  = (const float*)d_in[5];
  const float* W1  = (const float*)d_in[6];
  const float* b1  = (const float*)d_in[7];
  const float* W2  = (const float*)d_in[8];
  const float* b2  = (const float*)d_in[9];
  const float* g1  = (const float*)d_in[10];
  const float* be1 = (const float*)d_in[11];
  const float* g2  = (const float*)d_in[12];
  const float* be2 = (const float*)d_in[13];
  float* out = (float*)d_out;
  char* ws = (char*)d_ws;
  const size_t MB = 1024*1024;
  unsigned short* wq_t = (unsigned short*)(ws +  0*MB);  // stacked QKV^T: rows 0..3071
  unsigned short* wk_t = (unsigned short*)(ws +  2*MB);
  unsigned short* wv_t = (unsigned short*)(ws +  4*MB);
  unsigned short* wp_t = (unsigned short*)(ws +  6*MB);
  unsigned short* w1_t = (unsigned short*)(ws +  8*MB);
  unsigned short* w2_t = (unsigned short*)(ws + 16*MB);
  unsigned short* xn   = (unsigned short*)(ws + 24*MB);
  unsigned short* qb   = (unsigned short*)(ws + 32*MB);
  unsigned short* kb   = (unsigned short*)(ws + 40*MB);
  unsigned short* vtb  = (unsigned short*)(ws + 48*MB);
  unsigned short* yb   = (unsigned short*)(ws + 56*MB);
  float*          x2   = (float*)         (ws + 64*MB);
  unsigned short* xn2  = (unsigned short*)(ws + 80*MB);
  unsigned short* hb   = (unsigned short*)(ws + 88*MB);

  // weight transposes to B^T bf16 (head scale * log2e folded into Wq)
  transpose_cvt<<<dim3(16,16),256,0,stream>>>(Wq, wq_t, CH, CH, 0.18033688011112042f);
  transpose_cvt<<<dim3(16,16),256,0,stream>>>(Wk, wk_t, CH, CH, 1.f);
  transpose_cvt<<<dim3(16,16),256,0,stream>>>(Wv, wv_t, CH, CH, 1.f);
  transpose_cvt<<<dim3(16,16),256,0,stream>>>(Wp, wp_t, CH, CH, 1.f);
  transpose_cvt<<<dim3(64,16),256,0,stream>>>(W1, w1_t, CH, FF, 1.f);
  transpose_cvt<<<dim3(16,64),256,0,stream>>>(W2, w2_t, FF, CH, 1.f);

  ln_kernel<<<BN,256,0,stream>>>(x, g1, be1, xn);
  // fused QKV: Bt = stacked [3072][1024] starting at wq_t
  gemm128<0,0,0,3><<<dim3(24,32),256,0,stream>>>(xn, wq_t, nullptr, nullptr,
      nullptr, qb, kb, vtb, BN, 3072, CH);
  attn_kernel<<<dim3(16,32),256,0,stream>>>(qb, kb, vtb, yb);
  gemm_bt<64,1,0,1,0,0><<<dim3(16,32),256,0,stream>>>(yb, wp_t, bp, x, x2,
      nullptr, nullptr, nullptr, BN, CH, CH);
  ln_kernel<<<BN,256,0,stream>>>(x2, g2, be2, xn2);
  gemm128<1,1,0,1><<<dim3(32,32),256,0,stream>>>(xn2, w1_t, b1, nullptr, nullptr,
      hb, nullptr, nullptr, BN, FF, CH);
  // W2: single pass (no split-K, no memset, no atomics)
  gemm_bt<64,1,0,1,0,0><<<dim3(16,32),256,0,stream>>>(hb, w2_t, b2, x2, out,
      nullptr, nullptr, nullptr, BN, CH, FF);
}